// Round 13
// baseline (1420.577 us; speedup 1.0000x reference)
//
#include <hip/hip_runtime.h>
#include <hip/hip_bf16.h>

#define T_TASKS 8
#define B_ROWS 4096
#define PADROWS 4224      // +128 so partial-tile A reads stay in-bounds
#define BM 128
#define BN 128
#define BK 32
#define MAXTILES 40       // sum over tasks of ceil(cnt/BM) <= T + B/BM = 40

typedef __attribute__((ext_vector_type(4))) float f32x4;
typedef __attribute__((ext_vector_type(8))) short bf16x8;

struct TP { const float* src; unsigned short* dst; int K; int N; int ntiles; };

__device__ __forceinline__ unsigned short f32_to_bf16(float f) {
    union { float f; unsigned int u; } v; v.f = f;
    unsigned int r = v.u + 0x7FFF + ((v.u >> 16) & 1);  // RNE
    return (unsigned short)(r >> 16);
}

// ---------------- setup: counting sort by task + tile table ----------------
__global__ void setup_kernel(const int* __restrict__ task, int* __restrict__ perm,
                             int* __restrict__ offs, int* __restrict__ table) {
    __shared__ int cnt[T_TASKS];
    __shared__ int cur[T_TASKS];
    int tid = threadIdx.x;
    if (tid < T_TASKS) cnt[tid] = 0;
    __syncthreads();
    for (int b = tid; b < B_ROWS; b += blockDim.x)
        atomicAdd(&cnt[task[b]], 1);
    __syncthreads();
    if (tid == 0) {
        int o = 0;
        for (int t = 0; t < T_TASKS; ++t) { offs[t] = o; cur[t] = o; o += cnt[t]; }
        offs[T_TASKS] = o;
        int s = 0;
        for (int t = 0; t < T_TASKS; ++t) {
            int nt = (cnt[t] + BM - 1) / BM;
            for (int j = 0; j < nt; ++j) table[s++] = (t << 16) | j;
        }
        for (; s < MAXTILES; ++s) table[s] = -1;
    }
    __syncthreads();
    for (int b = tid; b < B_ROWS; b += blockDim.x) {
        int t = task[b];
        int pos = atomicAdd(&cur[t], 1);
        perm[pos] = b;
    }
}

// ---------------- permute + cast x -> bf16 ----------------
__global__ void permute_cast_kernel(const float* __restrict__ x, const int* __restrict__ perm,
                                    unsigned short* __restrict__ xp) {
    int rowp = blockIdx.x;
    int src = perm[rowp];
    const float4* xin = reinterpret_cast<const float4*>(x + (size_t)src * 1024);
    unsigned short* dst = xp + (size_t)rowp * 1024;
    int c4 = threadIdx.x;
    float4 v = xin[c4];
    ushort4 o;
    o.x = f32_to_bf16(v.x); o.y = f32_to_bf16(v.y);
    o.z = f32_to_bf16(v.z); o.w = f32_to_bf16(v.w);
    *reinterpret_cast<ushort4*>(dst + c4 * 4) = o;
}

// ---------------- VAE reparameterization ----------------
__global__ void vae_kernel(const float* __restrict__ scat, const float* __restrict__ eps,
                           const int* __restrict__ perm, unsigned short* __restrict__ z) {
    int rowp = blockIdx.x;
    int c = threadIdx.x;
    int src = perm[rowp];
    float mu = scat[(size_t)rowp * 512 + c];
    float ls = scat[(size_t)rowp * 512 + 256 + c];
    float e  = eps[(size_t)src * 256 + c];
    z[(size_t)rowp * 256 + c] = f32_to_bf16(mu + __expf(ls) * e);
}

// ---------------- standalone weight transpose (enc_W1 only) ----------------
__global__ __launch_bounds__(256)
void transpose_cast_kernel(const float* __restrict__ W, unsigned short* __restrict__ Wt,
                           int K, int N) {
    const size_t toff = (size_t)blockIdx.z * K * N;
    const float* Ws = W + toff;
    unsigned short* Wd = Wt + toff;
    const int k0 = blockIdx.x * 64;
    const int n0 = blockIdx.y * 64;
    __shared__ unsigned short Tt[64 * 64];
    const int tid = threadIdx.x;
    const int n = tid & 63;
    const int kq = tid >> 6;
    #pragma unroll
    for (int i = 0; i < 4; ++i) {
        int kk = kq * 16 + i * 4;
        const float* p = Ws + (size_t)(k0 + kk) * N + n0 + n;
        float v0 = p[0];
        float v1 = p[(size_t)N];
        float v2 = p[(size_t)2 * N];
        float v3 = p[(size_t)3 * N];
        unsigned int lo = (unsigned int)f32_to_bf16(v0) | ((unsigned int)f32_to_bf16(v1) << 16);
        unsigned int hi = (unsigned int)f32_to_bf16(v2) | ((unsigned int)f32_to_bf16(v3) << 16);
        int c = (kk >> 2) ^ (n & 15);
        *reinterpret_cast<uint2*>(Tt + n * 64 + c * 4) = make_uint2(lo, hi);
    }
    __syncthreads();
    #pragma unroll
    for (int it = 0; it < 2; ++it) {
        int c  = it * 256 + tid;
        int nn = c >> 3;
        int cg = c & 7;
        int c1 = (cg * 2) ^ (nn & 15);
        int c2 = (cg * 2 + 1) ^ (nn & 15);
        uint2 a = *reinterpret_cast<const uint2*>(Tt + nn * 64 + c1 * 4);
        uint2 b = *reinterpret_cast<const uint2*>(Tt + nn * 64 + c2 * 4);
        uint4 o = make_uint4(a.x, a.y, b.x, b.y);
        *reinterpret_cast<uint4*>(Wd + (size_t)(n0 + nn) * K + k0 + cg * 8) = o;
    }
}

// ---------------- zero-barrier zero-LDS grouped GEMM + transpose-role blocks ----------------
// Hypothesis (R6-R12 invariant): the K-loop __syncthreads' vmcnt(0) drain is the plateau.
// GEMM role has NO LDS and NO barriers: both fragments read DIRECTLY from global into
// registers (A bf16 [rowp][K] row-major, B bf16 [t][N][K] pre-transposed, both L3-resident;
// XCD remap gives same-task L2 locality). Per step/wave: 8 global_load_dwordx4 + 16 MFMA,
// register double-buffered (static banks) -> compiler pipelines with counted vmcnt freely.
// Frag mapping identical to proven LDS version: row rf=wr*64+m*16+(lane&15), kchunk (lane>>4)*8.
// Transpose role (bx >= GX): identical to R12 (own 8 KB LDS, GEMM role never touches it).
// MODE 0: relu -> bf16; MODE 1: f32 store; MODE 2: sigmoid -> f32 scatter via perm
template<int MODE>
__global__ __launch_bounds__(256, 2)
void gemm13_kernel(const unsigned short* __restrict__ A,
                   const unsigned short* __restrict__ Wt,
                   const float* __restrict__ bias, void* __restrict__ dst,
                   const int* __restrict__ offs, const int* __restrict__ table,
                   const int* __restrict__ perm,
                   int K, int N, int ldd, int Btot, int GX, TP tpa, TP tpb)
{
    __shared__ unsigned short Tt[64 * 64];      // transpose role only (8 KB)

    const int bxh = blockIdx.x;
    const int tid = threadIdx.x;

    if (bxh >= GX) {
        // ---------- transpose role (R12-identical) ----------
        int tile = (bxh - GX) * gridDim.y + blockIdx.y;
        const float* src; unsigned short* dstp; int tK, tN;
        if (tile < tpa.ntiles) { src = tpa.src; dstp = tpa.dst; tK = tpa.K; tN = tpa.N; }
        else {
            tile -= tpa.ntiles;
            if (tile >= tpb.ntiles) return;
            src = tpb.src; dstp = tpb.dst; tK = tpb.K; tN = tpb.N;
        }
        int tk = tK >> 6, tn = tN >> 6;
        int z = tile / (tk * tn);
        int r = tile % (tk * tn);
        int k0 = (r % tk) * 64, n0 = (r / tk) * 64;
        const size_t toff = (size_t)z * tK * tN;
        const float* Ws = src + toff;
        unsigned short* Wd = dstp + toff;
        const int n = tid & 63;
        const int kq = tid >> 6;
        #pragma unroll
        for (int i = 0; i < 4; ++i) {
            int kk = kq * 16 + i * 4;
            const float* p = Ws + (size_t)(k0 + kk) * tN + n0 + n;
            float v0 = p[0];
            float v1 = p[(size_t)tN];
            float v2 = p[(size_t)2 * tN];
            float v3 = p[(size_t)3 * tN];
            unsigned int lo = (unsigned int)f32_to_bf16(v0) | ((unsigned int)f32_to_bf16(v1) << 16);
            unsigned int hi = (unsigned int)f32_to_bf16(v2) | ((unsigned int)f32_to_bf16(v3) << 16);
            int c = (kk >> 2) ^ (n & 15);
            *reinterpret_cast<uint2*>(Tt + n * 64 + c * 4) = make_uint2(lo, hi);
        }
        __syncthreads();
        #pragma unroll
        for (int it = 0; it < 2; ++it) {
            int c  = it * 256 + tid;
            int nn = c >> 3;
            int cg = c & 7;
            int c1 = (cg * 2) ^ (nn & 15);
            int c2 = (cg * 2 + 1) ^ (nn & 15);
            uint2 a = *reinterpret_cast<const uint2*>(Tt + nn * 64 + c1 * 4);
            uint2 b = *reinterpret_cast<const uint2*>(Tt + nn * 64 + c2 * 4);
            uint4 o = make_uint4(a.x, a.y, b.x, b.y);
            *reinterpret_cast<uint4*>(Wd + (size_t)(n0 + nn) * tK + k0 + cg * 8) = o;
        }
        return;
    }

    // ---------- GEMM role ----------
    // XCD-chunked bijective bx remap (GX%8==0 and gridDim.x%8==0 in all launches)
    int bx = (bxh & 7) * (GX >> 3) + (bxh >> 3);

    int t, mtile, off, cnt;
    if (table != nullptr) {
        int v = table[bx];
        if (v < 0) return;
        t = v >> 16; mtile = v & 0xFFFF;
        off = offs[t]; cnt = offs[t + 1] - off;
    } else {
        t = 0; mtile = bx; off = 0; cnt = Btot;
    }
    const int n0 = blockIdx.y * BN;

    const int lane = tid & 63;
    const int wave = tid >> 6;
    const int wr = wave >> 1, wc = wave & 1;

    // per-lane frag base addresses (same logical mapping as the proven LDS version)
    const unsigned short* Abase =
        A + ((size_t)(off + mtile * BM + wr * 64 + (lane & 15))) * K + (lane >> 4) * 8;
    const unsigned short* Bbase =
        Wt + ((size_t)t * N + n0 + wc * 64 + (lane & 15)) * K + (lane >> 4) * 8;

    auto lf = [&](bf16x8 (&a)[4], bf16x8 (&b)[4], int k0) {
        #pragma unroll
        for (int m = 0; m < 4; ++m)
            a[m] = *reinterpret_cast<const bf16x8*>(Abase + (size_t)(m * 16) * K + k0);
        #pragma unroll
        for (int n = 0; n < 4; ++n)
            b[n] = *reinterpret_cast<const bf16x8*>(Bbase + (size_t)(n * 16) * K + k0);
    };

    f32x4 acc[4][4];
    #pragma unroll
    for (int m = 0; m < 4; ++m)
        #pragma unroll
        for (int n = 0; n < 4; ++n)
            acc[m][n] = (f32x4){0.f, 0.f, 0.f, 0.f};

    auto cm = [&](bf16x8 (&a)[4], bf16x8 (&b)[4]) {
        #pragma unroll
        for (int m = 0; m < 4; ++m)
            #pragma unroll
            for (int n = 0; n < 4; ++n)
                acc[m][n] = __builtin_amdgcn_mfma_f32_16x16x32_bf16(a[m], b[n], acc[m][n], 0, 0, 0);
    };

    // register double-buffer, static banks; no barriers, no LDS in this loop
    bf16x8 a0[4], b0[4], a1[4], b1[4];
    const int nsteps = K / BK;                  // even for all layers (8..64)
    lf(a0, b0, 0);
    for (int s = 0; s < nsteps; s += 2) {
        if (s + 1 < nsteps) lf(a1, b1, (s + 1) * BK);
        cm(a0, b0);
        if (s + 2 < nsteps) lf(a0, b0, (s + 2) * BK);
        cm(a1, b1);
    }

    // ---- epilogue (R12-identical) ----
    const float* bt = bias + (size_t)t * N;
    #pragma unroll
    for (int n = 0; n < 4; ++n) {
        int col = n0 + wc * 64 + n * 16 + (lane & 15);
        float bv = bt[col];
        #pragma unroll
        for (int m = 0; m < 4; ++m) {
            int rbase = mtile * BM + wr * 64 + m * 16 + ((lane >> 4) << 2);
            #pragma unroll
            for (int j = 0; j < 4; ++j) {
                int local = rbase + j;
                if (local >= cnt) continue;
                float v = acc[m][n][j] + bv;
                if (MODE == 0) {
                    ((unsigned short*)dst)[(size_t)(off + local) * ldd + col] =
                        f32_to_bf16(fmaxf(v, 0.f));
                } else if (MODE == 1) {
                    ((float*)dst)[(size_t)(off + local) * ldd + col] = v;
                } else {
                    int grow = perm[off + local];
                    ((float*)dst)[(size_t)grow * ldd + col] = 1.f / (1.f + __expf(-v));
                }
            }
        }
    }
}

extern "C" void kernel_launch(void* const* d_in, const int* in_sizes, int n_in,
                              void* d_out, int out_size, void* d_ws, size_t ws_size,
                              hipStream_t stream) {
    const float* x      = (const float*)d_in[0];
    const int*   task   = (const int*)d_in[1];
    const float* eps    = (const float*)d_in[2];
    const float* enc_W1 = (const float*)d_in[3];
    const float* enc_b1 = (const float*)d_in[4];
    const float* enc_W2 = (const float*)d_in[5];
    const float* enc_b2 = (const float*)d_in[6];
    const float* enc_W3 = (const float*)d_in[7];
    const float* enc_b3 = (const float*)d_in[8];
    const float* enc_W4 = (const float*)d_in[9];
    const float* enc_b4 = (const float*)d_in[10];
    const float* ds_W1  = (const float*)d_in[11];
    const float* ds_b1  = (const float*)d_in[12];
    const float* ds_W2  = (const float*)d_in[13];
    const float* ds_b2  = (const float*)d_in[14];
    const float* hd_W1  = (const float*)d_in[15];
    const float* hd_b1  = (const float*)d_in[16];
    const float* hd_W2  = (const float*)d_in[17];
    const float* hd_b2  = (const float*)d_in[18];
    float* out = (float*)d_out;

    // ---- workspace layout (~365 MB) ----
    char* ws = (char*)d_ws;
    int* perm  = (int*)ws;
    int* offs  = (int*)(ws + 16384);
    int* table = (int*)(ws + 16384 + 256);
    char* p = ws + 32768;
    unsigned short* xp = (unsigned short*)p; p += (size_t)PADROWS * 1024 * 2;
    unsigned short* h1 = (unsigned short*)p; p += (size_t)PADROWS * 2048 * 2;
    unsigned short* h2 = (unsigned short*)p; p += (size_t)PADROWS * 2048 * 2;
    unsigned short* zb = (unsigned short*)p; p += (size_t)PADROWS * 256 * 2;
    unsigned short* tw1  = (unsigned short*)p; p += (size_t)8 * 2048 * 1024 * 2;
    unsigned short* tw2  = (unsigned short*)p; p += (size_t)8 * 2048 * 2048 * 2;
    unsigned short* tw3  = (unsigned short*)p; p += (size_t)8 * 2048 * 2048 * 2;
    unsigned short* tw4  = (unsigned short*)p; p += (size_t)8 * 512 * 2048 * 2;
    unsigned short* tds1 = (unsigned short*)p; p += (size_t)2048 * 256 * 2;
    unsigned short* tds2 = (unsigned short*)p; p += (size_t)2048 * 2048 * 2;
    unsigned short* thd1 = (unsigned short*)p; p += (size_t)8 * 2048 * 2048 * 2;
    unsigned short* thd2 = (unsigned short*)p; p += (size_t)8 * 1024 * 2048 * 2;
    float* scat = out;   // reuse d_out as 8 MB scat scratch; fully overwritten later

    const TP tnone = { nullptr, nullptr, 64, 64, 0 };
    const TP tpW2  = { enc_W2, tw2, 2048, 2048, 8192 };
    const TP tpW3  = { enc_W3, tw3, 2048, 2048, 8192 };
    const TP tpW4  = { enc_W4, tw4, 2048,  512, 2048 };
    const TP tpDS1 = { ds_W1, tds1,  256, 2048,  128 };
    const TP tpDS2 = { ds_W2, tds2, 2048, 2048, 1024 };
    const TP tpHD1 = { hd_W1, thd1, 2048, 2048, 8192 };
    const TP tpHD2 = { hd_W2, thd2, 2048, 1024, 4096 };

    setup_kernel<<<1, 1024, 0, stream>>>(task, perm, offs, table);
    permute_cast_kernel<<<B_ROWS, 256, 0, stream>>>(x, perm, xp);

    // enc_W1 must be ready before the first GEMM -> standalone transpose
    transpose_cast_kernel<<<dim3(16, 32, 8), 256, 0, stream>>>(enc_W1, tw1, 1024, 2048);

    // All gridDim.x %8==0 (XCD remap validity).
    // D1: enc1 (y16) + transpose enc_W2 (8192/16=512) -> 552
    gemm13_kernel<0><<<dim3(552, 16), 256, 0, stream>>>(xp, tw1, enc_b1, h1, offs, table, nullptr, 1024, 2048, 2048, B_ROWS, MAXTILES, tpW2, tnone);
    // D2: enc2 + transpose enc_W3 -> 552
    gemm13_kernel<0><<<dim3(552, 16), 256, 0, stream>>>(h1, tw2, enc_b2, h2, offs, table, nullptr, 2048, 2048, 2048, B_ROWS, MAXTILES, tpW3, tnone);
    // D3: enc3 + transpose enc_W4 (2048) + ds_W1 (128): 2176/16=136 -> 176
    gemm13_kernel<0><<<dim3(176, 16), 256, 0, stream>>>(h2, tw3, enc_b3, h1, offs, table, nullptr, 2048, 2048, 2048, B_ROWS, MAXTILES, tpW4, tpDS1);
    // D4: enc4 (N=512, y=4) + transpose ds_W2 (1024/4=256) -> 296
    gemm13_kernel<1><<<dim3(296, 4), 256, 0, stream>>>(h1, tw4, enc_b4, scat, offs, table, nullptr, 2048, 512, 512, B_ROWS, MAXTILES, tpDS2, tnone);

    vae_kernel<<<B_ROWS, 256, 0, stream>>>(scat, eps, perm, zb);

    // D5: ds1 (ungrouped GX=32, K=256, y16) + transpose hd_W1 (8192/16=512) -> 544
    gemm13_kernel<0><<<dim3(544, 16), 256, 0, stream>>>(zb, tds1, ds_b1, h2, nullptr, nullptr, nullptr, 256, 2048, 2048, B_ROWS, 32, tpHD1, tnone);
    // D6: ds2 (ungrouped) + transpose hd_W2 (4096/16=256) -> 288
    gemm13_kernel<0><<<dim3(288, 16), 256, 0, stream>>>(h2, tds2, ds_b2, h1, nullptr, nullptr, nullptr, 2048, 2048, 2048, B_ROWS, 32, tpHD2, tnone);

    // D7: hd1 (grouped, pure)
    gemm13_kernel<0><<<dim3(MAXTILES, 16), 256, 0, stream>>>(h1, thd1, hd_b1, h2, offs, table, nullptr, 2048, 2048, 2048, B_ROWS, MAXTILES, tnone, tnone);
    // D8: hd2 (grouped, sigmoid scatter, N=1024, y=8)
    gemm13_kernel<2><<<dim3(MAXTILES, 8), 256, 0, stream>>>(h2, thd2, hd_b2, out, offs, table, perm, 2048, 1024, 1024, B_ROWS, MAXTILES, tnone, tnone);
}

// Round 14
// 652.718 us; speedup vs baseline: 2.1764x; 2.1764x over previous
//
#include <hip/hip_runtime.h>
#include <hip/hip_bf16.h>

#define T_TASKS 8
#define B_ROWS 4096
#define PADROWS 4224      // +128 so partial-tile A loads stay in-bounds
#define BM 128
#define BN 128
#define BK 32
#define MAXTILES 40       // sum over tasks of ceil(cnt/BM) <= T + B/BM = 40

typedef __attribute__((ext_vector_type(4))) float f32x4;
typedef __attribute__((ext_vector_type(8))) short bf16x8;

#define GLOAD_LDS16(g, l) __builtin_amdgcn_global_load_lds( \
    (const __attribute__((address_space(1))) void*)(g), \
    (__attribute__((address_space(3))) void*)(l), 16, 0, 0)

#define WAITV4() asm volatile("s_waitcnt vmcnt(4)" ::: "memory")
#define WAITV0() asm volatile("s_waitcnt vmcnt(0)" ::: "memory")

struct TP { const float* src; unsigned short* dst; int K; int N; int ntiles; };

__device__ __forceinline__ unsigned short f32_to_bf16(float f) {
    union { float f; unsigned int u; } v; v.f = f;
    unsigned int r = v.u + 0x7FFF + ((v.u >> 16) & 1);  // RNE
    return (unsigned short)(r >> 16);
}

// ---------------- setup: counting sort by task + tile table ----------------
__global__ void setup_kernel(const int* __restrict__ task, int* __restrict__ perm,
                             int* __restrict__ offs, int* __restrict__ table) {
    __shared__ int cnt[T_TASKS];
    __shared__ int cur[T_TASKS];
    int tid = threadIdx.x;
    if (tid < T_TASKS) cnt[tid] = 0;
    __syncthreads();
    for (int b = tid; b < B_ROWS; b += blockDim.x)
        atomicAdd(&cnt[task[b]], 1);
    __syncthreads();
    if (tid == 0) {
        int o = 0;
        for (int t = 0; t < T_TASKS; ++t) { offs[t] = o; cur[t] = o; o += cnt[t]; }
        offs[T_TASKS] = o;
        int s = 0;
        for (int t = 0; t < T_TASKS; ++t) {
            int nt = (cnt[t] + BM - 1) / BM;
            for (int j = 0; j < nt; ++j) table[s++] = (t << 16) | j;
        }
        for (; s < MAXTILES; ++s) table[s] = -1;
    }
    __syncthreads();
    for (int b = tid; b < B_ROWS; b += blockDim.x) {
        int t = task[b];
        int pos = atomicAdd(&cur[t], 1);
        perm[pos] = b;
    }
}

// ---------------- permute + cast x -> bf16 ----------------
__global__ void permute_cast_kernel(const float* __restrict__ x, const int* __restrict__ perm,
                                    unsigned short* __restrict__ xp) {
    int rowp = blockIdx.x;
    int src = perm[rowp];
    const float4* xin = reinterpret_cast<const float4*>(x + (size_t)src * 1024);
    unsigned short* dst = xp + (size_t)rowp * 1024;
    int c4 = threadIdx.x;
    float4 v = xin[c4];
    ushort4 o;
    o.x = f32_to_bf16(v.x); o.y = f32_to_bf16(v.y);
    o.z = f32_to_bf16(v.z); o.w = f32_to_bf16(v.w);
    *reinterpret_cast<ushort4*>(dst + c4 * 4) = o;
}

// ---------------- VAE reparameterization ----------------
__global__ void vae_kernel(const float* __restrict__ scat, const float* __restrict__ eps,
                           const int* __restrict__ perm, unsigned short* __restrict__ z) {
    int rowp = blockIdx.x;
    int c = threadIdx.x;
    int src = perm[rowp];
    float mu = scat[(size_t)rowp * 512 + c];
    float ls = scat[(size_t)rowp * 512 + 256 + c];
    float e  = eps[(size_t)src * 256 + c];
    z[(size_t)rowp * 256 + c] = f32_to_bf16(mu + __expf(ls) * e);
}

// ---------------- standalone weight transpose (enc_W1 only) ----------------
__global__ __launch_bounds__(256)
void transpose_cast_kernel(const float* __restrict__ W, unsigned short* __restrict__ Wt,
                           int K, int N) {
    const size_t toff = (size_t)blockIdx.z * K * N;
    const float* Ws = W + toff;
    unsigned short* Wd = Wt + toff;
    const int k0 = blockIdx.x * 64;
    const int n0 = blockIdx.y * 64;
    __shared__ unsigned short Tt[64 * 64];
    const int tid = threadIdx.x;
    const int n = tid & 63;
    const int kq = tid >> 6;
    #pragma unroll
    for (int i = 0; i < 4; ++i) {
        int kk = kq * 16 + i * 4;
        const float* p = Ws + (size_t)(k0 + kk) * N + n0 + n;
        float v0 = p[0];
        float v1 = p[(size_t)N];
        float v2 = p[(size_t)2 * N];
        float v3 = p[(size_t)3 * N];
        unsigned int lo = (unsigned int)f32_to_bf16(v0) | ((unsigned int)f32_to_bf16(v1) << 16);
        unsigned int hi = (unsigned int)f32_to_bf16(v2) | ((unsigned int)f32_to_bf16(v3) << 16);
        int c = (kk >> 2) ^ (n & 15);
        *reinterpret_cast<uint2*>(Tt + n * 64 + c * 4) = make_uint2(lo, hi);
    }
    __syncthreads();
    #pragma unroll
    for (int it = 0; it < 2; ++it) {
        int c  = it * 256 + tid;
        int nn = c >> 3;
        int cg = c & 7;
        int c1 = (cg * 2) ^ (nn & 15);
        int c2 = (cg * 2 + 1) ^ (nn & 15);
        uint2 a = *reinterpret_cast<const uint2*>(Tt + nn * 64 + c1 * 4);
        uint2 b = *reinterpret_cast<const uint2*>(Tt + nn * 64 + c2 * 4);
        uint4 o = make_uint4(a.x, a.y, b.x, b.y);
        *reinterpret_cast<uint4*>(Wd + (size_t)(n0 + nn) * K + k0 + cg * 8) = o;
    }
}

// ---------------- grouped GEMM: 3-buffer depth-2 counted-vmcnt pipeline ----------------
// R12 base (BN=128 bf16 B via global_load_lds, ride-along transposes, XCD remap,
// R6 swizzle) with ONLY the K-loop sync changed (T4, confound-free):
//   3 LDS buffers (48 KB), 4 gload_lds/wave/step. Per step s:
//     s_waitcnt vmcnt(4)   (own stage(s) landed; stage(s+1) stays in flight)
//     raw s_barrier        (=> ALL waves' stage(s) landed; NO vmcnt(0) drain)
//     stage(s+2) -> buf (s+2)%3   (readers of that buf finished before barrier s)
//     compute(s) from buf s%3
//   No sched_barrier (m141 trap), no reg-staged B (R9 trap), no occupancy loss (R7 trap):
//   grid 2.5 blocks/CU <= LDS cap 3, launch_bounds(256,3).
// MODE 0: relu -> bf16; MODE 1: f32 store; MODE 2: sigmoid -> f32 scatter via perm
template<int MODE>
__global__ __launch_bounds__(256, 3)
void gemm14_kernel(const unsigned short* __restrict__ A,
                   const unsigned short* __restrict__ Wt,
                   const float* __restrict__ bias, void* __restrict__ dst,
                   const int* __restrict__ offs, const int* __restrict__ table,
                   const int* __restrict__ perm,
                   int K, int N, int ldd, int Btot, int GX, TP tpa, TP tpb)
{
    __shared__ unsigned short As[3][BM * BK];   // 8 KB each
    __shared__ unsigned short Bs[3][BN * BK];   // 8 KB each (48 KB total)

    const int bxh = blockIdx.x;
    const int tid = threadIdx.x;

    if (bxh >= GX) {
        // ---------- transpose role (R12-identical; uses As[0] as its 8 KB tile) ----------
        int tile = (bxh - GX) * gridDim.y + blockIdx.y;
        const float* src; unsigned short* dstp; int tK, tN;
        if (tile < tpa.ntiles) { src = tpa.src; dstp = tpa.dst; tK = tpa.K; tN = tpa.N; }
        else {
            tile -= tpa.ntiles;
            if (tile >= tpb.ntiles) return;
            src = tpb.src; dstp = tpb.dst; tK = tpb.K; tN = tpb.N;
        }
        int tk = tK >> 6, tn = tN >> 6;
        int z = tile / (tk * tn);
        int r = tile % (tk * tn);
        int k0 = (r % tk) * 64, n0 = (r / tk) * 64;
        const size_t toff = (size_t)z * tK * tN;
        const float* Ws = src + toff;
        unsigned short* Wd = dstp + toff;
        unsigned short* Tt = &As[0][0];
        const int n = tid & 63;
        const int kq = tid >> 6;
        #pragma unroll
        for (int i = 0; i < 4; ++i) {
            int kk = kq * 16 + i * 4;
            const float* p = Ws + (size_t)(k0 + kk) * tN + n0 + n;
            float v0 = p[0];
            float v1 = p[(size_t)tN];
            float v2 = p[(size_t)2 * tN];
            float v3 = p[(size_t)3 * tN];
            unsigned int lo = (unsigned int)f32_to_bf16(v0) | ((unsigned int)f32_to_bf16(v1) << 16);
            unsigned int hi = (unsigned int)f32_to_bf16(v2) | ((unsigned int)f32_to_bf16(v3) << 16);
            int c = (kk >> 2) ^ (n & 15);
            *reinterpret_cast<uint2*>(Tt + n * 64 + c * 4) = make_uint2(lo, hi);
        }
        __syncthreads();
        #pragma unroll
        for (int it = 0; it < 2; ++it) {
            int c  = it * 256 + tid;
            int nn = c >> 3;
            int cg = c & 7;
            int c1 = (cg * 2) ^ (nn & 15);
            int c2 = (cg * 2 + 1) ^ (nn & 15);
            uint2 a = *reinterpret_cast<const uint2*>(Tt + nn * 64 + c1 * 4);
            uint2 b = *reinterpret_cast<const uint2*>(Tt + nn * 64 + c2 * 4);
            uint4 o = make_uint4(a.x, a.y, b.x, b.y);
            *reinterpret_cast<uint4*>(Wd + (size_t)(n0 + nn) * tK + k0 + cg * 8) = o;
        }
        return;
    }

    // ---------- GEMM role ----------
    // XCD-chunked bijective bx remap (GX%8==0 and gridDim.x%8==0 in all launches)
    int bx = (bxh & 7) * (GX >> 3) + (bxh >> 3);

    int t, mtile, off, cnt;
    if (table != nullptr) {
        int v = table[bx];
        if (v < 0) return;
        t = v >> 16; mtile = v & 0xFFFF;
        off = offs[t]; cnt = offs[t + 1] - off;
    } else {
        t = 0; mtile = bx; off = 0; cnt = Btot;
    }
    const int n0 = blockIdx.y * BN;

    const int lane = tid & 63;
    const int wave = tid >> 6;
    const int wr = wave >> 1, wc = wave & 1;

    // staging geometry (R6-proven): lane -> row rl=lane>>2 in a 16-row line,
    // chunk lane&3, source chunk XOR ((rl>>1)&3). LDS dest linear.
    const int rl   = lane >> 2;                 // 0..15
    const int csrc = ((lane & 3) ^ ((rl >> 1) & 3)) * 8;
    const unsigned short* Ab = A + ((size_t)(off + mtile * BM + rl)) * K + csrc;
    const unsigned short* Bb = Wt + ((size_t)t * N + n0 + rl) * K + csrc;

    auto stage = [&](int buf, int k0) {
        #pragma unroll
        for (int jj = 0; jj < 2; ++jj) {
            int j = wave * 2 + jj;              // A: 8 lines of 16 rows
            GLOAD_LDS16(Ab + (size_t)(j * 16) * K + k0, &As[buf][j * 512]);
        }
        #pragma unroll
        for (int jb = 0; jb < 2; ++jb) {
            int j = wave * 2 + jb;              // B: 8 lines of 16 rows
            GLOAD_LDS16(Bb + (size_t)(j * 16) * K + k0, &Bs[buf][j * 512]);
        }
    };

    f32x4 acc[4][4];
    #pragma unroll
    for (int m = 0; m < 4; ++m)
        #pragma unroll
        for (int n = 0; n < 4; ++n)
            acc[m][n] = (f32x4){0.f, 0.f, 0.f, 0.f};

    auto compute = [&](int buf) {
        bf16x8 af[4], bfr[4];
        #pragma unroll
        for (int m = 0; m < 4; ++m) {
            int rf = wr * 64 + m * 16 + (lane & 15);
            af[m] = *reinterpret_cast<const bf16x8*>(
                &As[buf][rf * 32 + (((lane >> 4) ^ ((rf >> 1) & 3)) * 8)]);
        }
        #pragma unroll
        for (int n = 0; n < 4; ++n) {
            int nf = wc * 64 + n * 16 + (lane & 15);
            bfr[n] = *reinterpret_cast<const bf16x8*>(
                &Bs[buf][nf * 32 + (((lane >> 4) ^ ((nf >> 1) & 3)) * 8)]);
        }
        #pragma unroll
        for (int m = 0; m < 4; ++m)
            #pragma unroll
            for (int n = 0; n < 4; ++n)
                acc[m][n] = __builtin_amdgcn_mfma_f32_16x16x32_bf16(af[m], bfr[n], acc[m][n], 0, 0, 0);
    };

    // ---- depth-2 pipeline: vmcnt never 0 in the main loop ----
    const int nsteps = K / BK;                  // 8..64
    stage(0, 0);
    stage(1, BK);                               // 8 loads outstanding
    int cur = 0;
    for (int s = 0; s < nsteps - 1; ++s) {
        WAITV4();                               // own stage(s) landed
        __builtin_amdgcn_s_barrier();           // all waves' stage(s) landed
        if (s + 2 < nsteps) {
            int tgt = cur + 2; if (tgt >= 3) tgt -= 3;
            stage(tgt, (s + 2) * BK);           // issue-early: 2 steps of slack
        }
        compute(cur);
        ++cur; if (cur == 3) cur = 0;
    }
    WAITV0();
    __builtin_amdgcn_s_barrier();
    compute(cur);

    // ---- epilogue (R12-identical) ----
    const float* bt = bias + (size_t)t * N;
    #pragma unroll
    for (int n = 0; n < 4; ++n) {
        int col = n0 + wc * 64 + n * 16 + (lane & 15);
        float bv = bt[col];
        #pragma unroll
        for (int m = 0; m < 4; ++m) {
            int rbase = mtile * BM + wr * 64 + m * 16 + ((lane >> 4) << 2);
            #pragma unroll
            for (int j = 0; j < 4; ++j) {
                int local = rbase + j;
                if (local >= cnt) continue;
                float v = acc[m][n][j] + bv;
                if (MODE == 0) {
                    ((unsigned short*)dst)[(size_t)(off + local) * ldd + col] =
                        f32_to_bf16(fmaxf(v, 0.f));
                } else if (MODE == 1) {
                    ((float*)dst)[(size_t)(off + local) * ldd + col] = v;
                } else {
                    int grow = perm[off + local];
                    ((float*)dst)[(size_t)grow * ldd + col] = 1.f / (1.f + __expf(-v));
                }
            }
        }
    }
}

extern "C" void kernel_launch(void* const* d_in, const int* in_sizes, int n_in,
                              void* d_out, int out_size, void* d_ws, size_t ws_size,
                              hipStream_t stream) {
    const float* x      = (const float*)d_in[0];
    const int*   task   = (const int*)d_in[1];
    const float* eps    = (const float*)d_in[2];
    const float* enc_W1 = (const float*)d_in[3];
    const float* enc_b1 = (const float*)d_in[4];
    const float* enc_W2 = (const float*)d_in[5];
    const float* enc_b2 = (const float*)d_in[6];
    const float* enc_W3 = (const float*)d_in[7];
    const float* enc_b3 = (const float*)d_in[8];
    const float* enc_W4 = (const float*)d_in[9];
    const float* enc_b4 = (const float*)d_in[10];
    const float* ds_W1  = (const float*)d_in[11];
    const float* ds_b1  = (const float*)d_in[12];
    const float* ds_W2  = (const float*)d_in[13];
    const float* ds_b2  = (const float*)d_in[14];
    const float* hd_W1  = (const float*)d_in[15];
    const float* hd_b1  = (const float*)d_in[16];
    const float* hd_W2  = (const float*)d_in[17];
    const float* hd_b2  = (const float*)d_in[18];
    float* out = (float*)d_out;

    // ---- workspace layout (~365 MB) ----
    char* ws = (char*)d_ws;
    int* perm  = (int*)ws;
    int* offs  = (int*)(ws + 16384);
    int* table = (int*)(ws + 16384 + 256);
    char* p = ws + 32768;
    unsigned short* xp = (unsigned short*)p; p += (size_t)PADROWS * 1024 * 2;
    unsigned short* h1 = (unsigned short*)p; p += (size_t)PADROWS * 2048 * 2;
    unsigned short* h2 = (unsigned short*)p; p += (size_t)PADROWS * 2048 * 2;
    unsigned short* zb = (unsigned short*)p; p += (size_t)PADROWS * 256 * 2;
    unsigned short* tw1  = (unsigned short*)p; p += (size_t)8 * 2048 * 1024 * 2;
    unsigned short* tw2  = (unsigned short*)p; p += (size_t)8 * 2048 * 2048 * 2;
    unsigned short* tw3  = (unsigned short*)p; p += (size_t)8 * 2048 * 2048 * 2;
    unsigned short* tw4  = (unsigned short*)p; p += (size_t)8 * 512 * 2048 * 2;
    unsigned short* tds1 = (unsigned short*)p; p += (size_t)2048 * 256 * 2;
    unsigned short* tds2 = (unsigned short*)p; p += (size_t)2048 * 2048 * 2;
    unsigned short* thd1 = (unsigned short*)p; p += (size_t)8 * 2048 * 2048 * 2;
    unsigned short* thd2 = (unsigned short*)p; p += (size_t)8 * 1024 * 2048 * 2;
    float* scat = out;   // reuse d_out as 8 MB scat scratch; fully overwritten later

    const TP tnone = { nullptr, nullptr, 64, 64, 0 };
    const TP tpW2  = { enc_W2, tw2, 2048, 2048, 8192 };
    const TP tpW3  = { enc_W3, tw3, 2048, 2048, 8192 };
    const TP tpW4  = { enc_W4, tw4, 2048,  512, 2048 };
    const TP tpDS1 = { ds_W1, tds1,  256, 2048,  128 };
    const TP tpDS2 = { ds_W2, tds2, 2048, 2048, 1024 };
    const TP tpHD1 = { hd_W1, thd1, 2048, 2048, 8192 };
    const TP tpHD2 = { hd_W2, thd2, 2048, 1024, 4096 };

    setup_kernel<<<1, 1024, 0, stream>>>(task, perm, offs, table);
    permute_cast_kernel<<<B_ROWS, 256, 0, stream>>>(x, perm, xp);

    // enc_W1 must be ready before the first GEMM -> standalone transpose
    transpose_cast_kernel<<<dim3(16, 32, 8), 256, 0, stream>>>(enc_W1, tw1, 1024, 2048);

    // All gridDim.x %8==0 (XCD remap validity).
    // D1: enc1 (y16) + transpose enc_W2 (8192/16=512) -> 552
    gemm14_kernel<0><<<dim3(552, 16), 256, 0, stream>>>(xp, tw1, enc_b1, h1, offs, table, nullptr, 1024, 2048, 2048, B_ROWS, MAXTILES, tpW2, tnone);
    // D2: enc2 + transpose enc_W3 -> 552
    gemm14_kernel<0><<<dim3(552, 16), 256, 0, stream>>>(h1, tw2, enc_b2, h2, offs, table, nullptr, 2048, 2048, 2048, B_ROWS, MAXTILES, tpW3, tnone);
    // D3: enc3 + transpose enc_W4 (2048) + ds_W1 (128): 2176/16=136 -> 176
    gemm14_kernel<0><<<dim3(176, 16), 256, 0, stream>>>(h2, tw3, enc_b3, h1, offs, table, nullptr, 2048, 2048, 2048, B_ROWS, MAXTILES, tpW4, tpDS1);
    // D4: enc4 (N=512, y=4) + transpose ds_W2 (1024/4=256) -> 296
    gemm14_kernel<1><<<dim3(296, 4), 256, 0, stream>>>(h1, tw4, enc_b4, scat, offs, table, nullptr, 2048, 512, 512, B_ROWS, MAXTILES, tpDS2, tnone);

    vae_kernel<<<B_ROWS, 256, 0, stream>>>(scat, eps, perm, zb);

    // D5: ds1 (ungrouped GX=32, K=256, y16) + transpose hd_W1 (8192/16=512) -> 544
    gemm14_kernel<0><<<dim3(544, 16), 256, 0, stream>>>(zb, tds1, ds_b1, h2, nullptr, nullptr, nullptr, 256, 2048, 2048, B_ROWS, 32, tpHD1, tnone);
    // D6: ds2 (ungrouped) + transpose hd_W2 (4096/16=256) -> 288
    gemm14_kernel<0><<<dim3(288, 16), 256, 0, stream>>>(h2, tds2, ds_b2, h1, nullptr, nullptr, nullptr, 2048, 2048, 2048, B_ROWS, 32, tpHD2, tnone);

    // D7: hd1 (grouped, pure)
    gemm14_kernel<0><<<dim3(MAXTILES, 16), 256, 0, stream>>>(h1, thd1, hd_b1, h2, offs, table, nullptr, 2048, 2048, 2048, B_ROWS, MAXTILES, tnone, tnone);
    // D8: hd2 (grouped, sigmoid scatter, N=1024, y=8)
    gemm14_kernel<2><<<dim3(MAXTILES, 8), 256, 0, stream>>>(h2, thd2, hd_b2, out, offs, table, perm, 2048, 1024, 1024, B_ROWS, MAXTILES, tnone, tnone);
}